// Round 2
// baseline (611.178 us; speedup 1.0000x reference)
//
#include <hip/hip_runtime.h>

typedef __attribute__((ext_vector_type(8))) short short8;
typedef __attribute__((ext_vector_type(4))) float floatx4;
typedef __attribute__((ext_vector_type(4))) int intx4;

#define NPIX 4096
#define CH 256

static __device__ __forceinline__ unsigned short f2bf(float f) {
  union { float f; unsigned int u; } v; v.f = f;
  unsigned int u = v.u;
  return (unsigned short)((u + 0x7FFFu + ((u >> 16) & 1u)) >> 16);
}

typedef __attribute__((address_space(3))) unsigned int lds_uint;
typedef const __attribute__((address_space(1))) unsigned int glob_uint;
static __device__ __forceinline__ void gload16(const void* g, void* l) {
  __builtin_amdgcn_global_load_lds((glob_uint*)g, (lds_uint*)l, 16, 0, 0);
}

// ---------------- weights fp32 -> bf16 ----------------
__global__ void conv_weights_kernel(const float* __restrict__ wq, const float* __restrict__ wk,
                                    const float* __restrict__ wv, const float* __restrict__ wo,
                                    unsigned short* __restrict__ wqkv, unsigned short* __restrict__ wob) {
  int i = blockIdx.x * 256 + threadIdx.x;   // 0..65535
  wqkv[i]          = f2bf(wq[i]);
  wqkv[65536 + i]  = f2bf(wk[i]);
  wqkv[131072 + i] = f2bf(wv[i]);
  wob[i]           = f2bf(wo[i]);
}

// ---------------- GroupNorm -> xnT bf16 [b][n][c] ----------------
__global__ __launch_bounds__(256) void gn_kernel(const float* __restrict__ x,
                                                 const float* __restrict__ gsc,
                                                 const float* __restrict__ gbi,
                                                 unsigned short* __restrict__ xnT) {
  int blk = blockIdx.x; int b = blk >> 5; int g = blk & 31;
  int c0 = g * 8;
  const float* xb = x + ((size_t)b * CH + c0) * NPIX;
  int tid = threadIdx.x;
  float s = 0.f, ss = 0.f;
#pragma unroll
  for (int ci = 0; ci < 8; ++ci) {
    const floatx4* p = (const floatx4*)(xb + (size_t)ci * NPIX);
    for (int n4 = tid; n4 < 1024; n4 += 256) {
      floatx4 v = p[n4];
      s += v[0] + v[1] + v[2] + v[3];
      ss += v[0]*v[0] + v[1]*v[1] + v[2]*v[2] + v[3]*v[3];
    }
  }
#pragma unroll
  for (int o = 32; o > 0; o >>= 1) { s += __shfl_down(s, o); ss += __shfl_down(ss, o); }
  __shared__ float red[10];
  int wid = tid >> 6;
  if ((tid & 63) == 0) { red[wid] = s; red[4 + wid] = ss; }
  __syncthreads();
  if (tid == 0) {
    float S = red[0] + red[1] + red[2] + red[3];
    float SS = red[4] + red[5] + red[6] + red[7];
    float mean = S * (1.f / 32768.f);
    float var = SS * (1.f / 32768.f) - mean * mean;
    red[8] = mean; red[9] = rsqrtf(var + 1e-5f);
  }
  __syncthreads();
  float mean = red[8], rstd = red[9];
  float sc[8], bi[8];
#pragma unroll
  for (int ci = 0; ci < 8; ++ci) {
    float scale = gsc[c0 + ci] * rstd;
    sc[ci] = scale;
    bi[ci] = gbi[c0 + ci] - mean * scale;
  }
  for (int n4 = tid; n4 < 1024; n4 += 256) {
    floatx4 v[8];
#pragma unroll
    for (int ci = 0; ci < 8; ++ci) v[ci] = ((const floatx4*)(xb + (size_t)ci * NPIX))[n4];
#pragma unroll
    for (int j = 0; j < 4; ++j) {
      alignas(16) unsigned short tmp[8];
#pragma unroll
      for (int ci = 0; ci < 8; ++ci) tmp[ci] = f2bf(v[ci][j] * sc[ci] + bi[ci]);
      *(intx4*)(xnT + ((size_t)(b * NPIX + n4 * 4 + j)) * CH + c0) = *(const intx4*)tmp;
    }
  }
}

// ---------------- QKV GEMM: D[o,n] = sum_c W[o,c]*xnT[n,c] + bias ----------------
// q (pre-scaled by 1/16), k written [n][o] bf16 ; v written [o][n] bf16
__global__ __launch_bounds__(256, 2) void qkv_gemm(
    const unsigned short* __restrict__ wqkv, const unsigned short* __restrict__ xnT,
    const float* __restrict__ bq, const float* __restrict__ bk, const float* __restrict__ bv,
    unsigned short* __restrict__ qT, unsigned short* __restrict__ kT, unsigned short* __restrict__ vC) {
  int nt = blockIdx.x, ot = blockIdx.y, bz = blockIdx.z;
  int which = bz % 3, b = bz / 3;
  const unsigned short* W = wqkv + which * 65536;
  const float* bias = which == 0 ? bq : (which == 1 ? bk : bv);
  const unsigned short* X = xnT + (size_t)b * NPIX * CH;
  int o0 = ot * 128, n0 = nt * 128;

  __shared__ unsigned short As[128 * 64];
  __shared__ unsigned short Bs[128 * 64];

  int tid = threadIdx.x;
  int wave = tid >> 6, lane = tid & 63, quad = lane >> 4, l16 = lane & 15;
  int wm = (wave >> 1) * 64, wn = (wave & 1) * 64;

  floatx4 acc[4][4];
#pragma unroll
  for (int i = 0; i < 4; ++i)
#pragma unroll
    for (int j = 0; j < 4; ++j) acc[i][j] = (floatx4){0.f, 0.f, 0.f, 0.f};

  for (int k0 = 0; k0 < 256; k0 += 64) {
    __syncthreads();
#pragma unroll
    for (int c2 = 0; c2 < 4; ++c2) {
      int row = wave * 32 + c2 * 8 + (lane >> 3);
      int sc = (lane & 7) ^ (row & 7);
      gload16(W + (size_t)(o0 + row) * CH + k0 + sc * 8, &As[(wave * 32 + c2 * 8) * 64]);
      gload16(X + (size_t)(n0 + row) * CH + k0 + sc * 8, &Bs[(wave * 32 + c2 * 8) * 64]);
    }
    __syncthreads();
#pragma unroll
    for (int s = 0; s < 2; ++s) {
      short8 af[4], bf[4];
#pragma unroll
      for (int i = 0; i < 4; ++i) {
        int m = wm + i * 16 + l16;
        af[i] = *(const short8*)(As + m * 64 + (((s * 4 + quad) ^ (m & 7)) * 8));
        int n = wn + i * 16 + l16;
        bf[i] = *(const short8*)(Bs + n * 64 + (((s * 4 + quad) ^ (n & 7)) * 8));
      }
#pragma unroll
      for (int i = 0; i < 4; ++i)
#pragma unroll
        for (int j = 0; j < 4; ++j)
          acc[i][j] = __builtin_amdgcn_mfma_f32_16x16x32_bf16(af[i], bf[j], acc[i][j], 0, 0, 0);
    }
  }

  if (which < 2) {
    float qs = (which == 0) ? 0.0625f : 1.0f;   // fold 1/sqrt(256) into Q
    unsigned short* outp = (which == 0 ? qT : kT) + (size_t)b * NPIX * CH;
#pragma unroll
    for (int i = 0; i < 4; ++i) {
      int obase = o0 + wm + i * 16 + quad * 4;
      float bias4[4];
#pragma unroll
      for (int r = 0; r < 4; ++r) bias4[r] = bias[obase + r];
#pragma unroll
      for (int j = 0; j < 4; ++j) {
        int n = n0 + wn + j * 16 + l16;
        unsigned long long pk = 0;
#pragma unroll
        for (int r = 0; r < 4; ++r)
          pk |= (unsigned long long)f2bf((acc[i][j][r] + bias4[r]) * qs) << (16 * r);
        *(unsigned long long*)(outp + (size_t)n * CH + obase) = pk;
      }
    }
  } else {
    unsigned short* outp = vC + (size_t)b * CH * NPIX;
#pragma unroll
    for (int i = 0; i < 4; ++i)
#pragma unroll
      for (int r = 0; r < 4; ++r) {
        int o = o0 + wm + i * 16 + quad * 4 + r;
        float bb = bias[o];
#pragma unroll
        for (int j = 0; j < 4; ++j) {
          int n = n0 + wn + j * 16 + l16;
          outp[(size_t)o * NPIX + n] = f2bf(acc[i][j][r] + bb);
        }
      }
  }
}

// ---------------- flash attention (S^T form, 2-way K-split) ----------------
// grid (32, 2, 8), block 256 (4 waves x 32 Q-rows = 128 q/block). BK=64.
// Writes unnormalized partial O [split][b][q][c] fp32 + (m,l) per q.
__global__ __launch_bounds__(256, 2) void attn_kernel(
    const unsigned short* __restrict__ qT, const unsigned short* __restrict__ kT,
    const unsigned short* __restrict__ vC, float* __restrict__ Opart, float* __restrict__ ml) {
  __shared__ unsigned short Klds[64 * 256];   // 32KB: [k-row][c], chunk-swizzled
  __shared__ unsigned short Vlds[256 * 64];   // 32KB: [c][m], chunk-swizzled
  __shared__ unsigned short Plds[4][32 * 64]; // 16KB: per-wave P [q][k]

  const int tid = threadIdx.x;
  const int wave = tid >> 6, lane = tid & 63;
  const int quad = lane >> 4, l16 = lane & 15;
  const int b = blockIdx.z, split = blockIdx.y;
  const int q0 = blockIdx.x * 128 + wave * 32;

  const unsigned short* Kb = kT + (size_t)b * NPIX * CH;
  const unsigned short* Vb = vC + (size_t)b * CH * NPIX;

  // Q fragments: B[n=q][k=c]; q in regs for two 16-blocks
  short8 qf[2][8];
#pragma unroll
  for (int qb = 0; qb < 2; ++qb) {
    const unsigned short* qp = qT + ((size_t)(b * NPIX + q0 + qb * 16 + l16)) * CH + quad * 8;
#pragma unroll
    for (int s = 0; s < 8; ++s) qf[qb][s] = *(const short8*)(qp + s * 32);
  }

  floatx4 oacc0[16], oacc1[16];   // O^T: [cb] -> D[c][q]
#pragma unroll
  for (int j = 0; j < 16; ++j) { oacc0[j] = (floatx4){0,0,0,0}; oacc1[j] = (floatx4){0,0,0,0}; }
  float m_i0 = -1e30f, l_i0 = 0.f, m_i1 = -1e30f, l_i1 = 0.f;

  unsigned short* Pw = Plds[wave];

  for (int kt = 0; kt < 32; ++kt) {
    const int m0 = (split * 32 + kt) * 64;
    __syncthreads();
#pragma unroll
    for (int c2 = 0; c2 < 8; ++c2) {
      int krow = wave * 16 + c2 * 2 + (lane >> 5);
      gload16(Kb + (size_t)(m0 + krow) * CH + (((lane & 31) ^ (krow & 7)) * 8),
              &Klds[(wave * 16 + c2 * 2) * CH]);
      int vrow = wave * 64 + c2 * 8 + (lane >> 3);
      gload16(Vb + (size_t)vrow * NPIX + m0 + (((lane & 7) ^ (vrow & 7)) * 8),
              &Vlds[(wave * 64 + c2 * 8) * 64]);
    }
    __syncthreads();

    // S^T = K Q^T : D[k][q], each kf read feeds both q-blocks
    floatx4 sacc0[4], sacc1[4];
#pragma unroll
    for (int kb = 0; kb < 4; ++kb) { sacc0[kb] = (floatx4){0,0,0,0}; sacc1[kb] = (floatx4){0,0,0,0}; }
#pragma unroll
    for (int s = 0; s < 8; ++s) {
#pragma unroll
      for (int kb = 0; kb < 4; ++kb) {
        int m = kb * 16 + l16;
        short8 kf = *(const short8*)&Klds[m * CH + (((s * 4 + quad) ^ (m & 7)) * 8)];
        sacc0[kb] = __builtin_amdgcn_mfma_f32_16x16x32_bf16(kf, qf[0][s], sacc0[kb], 0, 0, 0);
        sacc1[kb] = __builtin_amdgcn_mfma_f32_16x16x32_bf16(kf, qf[1][s], sacc1[kb], 0, 0, 0);
      }
    }

    // online softmax, per-lane q (scale pre-folded into Q)
    float alpha0, alpha1;
    {
      float mx = sacc0[0][0];
#pragma unroll
      for (int kb = 0; kb < 4; ++kb)
#pragma unroll
        for (int r = 0; r < 4; ++r) mx = fmaxf(mx, sacc0[kb][r]);
      mx = fmaxf(mx, __shfl_xor(mx, 16));
      mx = fmaxf(mx, __shfl_xor(mx, 32));
      float mn = fmaxf(m_i0, mx);
      alpha0 = __expf(m_i0 - mn); m_i0 = mn;
      float sum = 0.f;
#pragma unroll
      for (int kb = 0; kb < 4; ++kb)
#pragma unroll
        for (int r = 0; r < 4; ++r) { float p = __expf(sacc0[kb][r] - mn); sacc0[kb][r] = p; sum += p; }
      sum += __shfl_xor(sum, 16);
      sum += __shfl_xor(sum, 32);
      l_i0 = l_i0 * alpha0 + sum;
    }
    {
      float mx = sacc1[0][0];
#pragma unroll
      for (int kb = 0; kb < 4; ++kb)
#pragma unroll
        for (int r = 0; r < 4; ++r) mx = fmaxf(mx, sacc1[kb][r]);
      mx = fmaxf(mx, __shfl_xor(mx, 16));
      mx = fmaxf(mx, __shfl_xor(mx, 32));
      float mn = fmaxf(m_i1, mx);
      alpha1 = __expf(m_i1 - mn); m_i1 = mn;
      float sum = 0.f;
#pragma unroll
      for (int kb = 0; kb < 4; ++kb)
#pragma unroll
        for (int r = 0; r < 4; ++r) { float p = __expf(sacc1[kb][r] - mn); sacc1[kb][r] = p; sum += p; }
      sum += __shfl_xor(sum, 16);
      sum += __shfl_xor(sum, 32);
      l_i1 = l_i1 * alpha1 + sum;
    }

    // P -> per-wave LDS (packed b64 writes), rows q, cols k
#pragma unroll
    for (int kb = 0; kb < 4; ++kb) {
      int phys = (kb * 2 + (quad >> 1)) ^ (l16 & 7);
      int off = phys * 8 + (quad & 1) * 4;
      uint2 w0, w1;
      w0.x = (unsigned int)f2bf(sacc0[kb][0]) | ((unsigned int)f2bf(sacc0[kb][1]) << 16);
      w0.y = (unsigned int)f2bf(sacc0[kb][2]) | ((unsigned int)f2bf(sacc0[kb][3]) << 16);
      w1.x = (unsigned int)f2bf(sacc1[kb][0]) | ((unsigned int)f2bf(sacc1[kb][1]) << 16);
      w1.y = (unsigned int)f2bf(sacc1[kb][2]) | ((unsigned int)f2bf(sacc1[kb][3]) << 16);
      *(uint2*)&Pw[l16 * 64 + off] = w0;
      *(uint2*)&Pw[(16 + l16) * 64 + off] = w1;
    }

    // rescale O while P writes drain
#pragma unroll
    for (int cb = 0; cb < 16; ++cb)
#pragma unroll
      for (int r = 0; r < 4; ++r) { oacc0[cb][r] *= alpha0; oacc1[cb][r] *= alpha1; }

    asm volatile("s_waitcnt lgkmcnt(0)" ::: "memory");
    short8 pf00 = *(const short8*)&Pw[l16 * 64 + ((quad ^ (l16 & 7)) * 8)];
    short8 pf01 = *(const short8*)&Pw[l16 * 64 + (((4 + quad) ^ (l16 & 7)) * 8)];
    short8 pf10 = *(const short8*)&Pw[(16 + l16) * 64 + ((quad ^ (l16 & 7)) * 8)];
    short8 pf11 = *(const short8*)&Pw[(16 + l16) * 64 + (((4 + quad) ^ (l16 & 7)) * 8)];

    // O^T += V P^T : each vf read feeds both q-blocks
#pragma unroll
    for (int h = 0; h < 2; ++h) {
#pragma unroll
      for (int cb = 0; cb < 16; ++cb) {
        int c = cb * 16 + l16;
        short8 vf = *(const short8*)&Vlds[c * 64 + (((h * 4 + quad) ^ (c & 7)) * 8)];
        oacc0[cb] = __builtin_amdgcn_mfma_f32_16x16x32_bf16(vf, h ? pf01 : pf00, oacc0[cb], 0, 0, 0);
        oacc1[cb] = __builtin_amdgcn_mfma_f32_16x16x32_bf16(vf, h ? pf11 : pf10, oacc1[cb], 0, 0, 0);
      }
    }
  }

  // epilogue: partial O (fp32) + (m,l)
  {
    int q = q0 + l16;
    float* op = Opart + ((size_t)(split * 8 + b) * NPIX + q) * CH + quad * 4;
#pragma unroll
    for (int cb = 0; cb < 16; ++cb) *(floatx4*)(op + cb * 16) = oacc0[cb];
    if (quad == 0) {
      float* mp = ml + ((size_t)(split * 8 + b) * NPIX + q) * 2;
      mp[0] = m_i0; mp[1] = l_i0;
    }
  }
  {
    int q = q0 + 16 + l16;
    float* op = Opart + ((size_t)(split * 8 + b) * NPIX + q) * CH + quad * 4;
#pragma unroll
    for (int cb = 0; cb < 16; ++cb) *(floatx4*)(op + cb * 16) = oacc1[cb];
    if (quad == 0) {
      float* mp = ml + ((size_t)(split * 8 + b) * NPIX + q) * 2;
      mp[0] = m_i1; mp[1] = l_i1;
    }
  }
}

// ---------------- combine the 2 K-split partials -> aT bf16 [n][c] ----------------
__global__ __launch_bounds__(256) void combine_kernel(const float* __restrict__ Opart,
                                                      const float* __restrict__ ml,
                                                      unsigned short* __restrict__ aT) {
  int t = blockIdx.x * 256 + threadIdx.x;   // 1M threads, 8 c each
  int qg = t >> 5;
  int coff = (t & 31) << 3;
  float2 a = *(const float2*)(ml + (size_t)qg * 2);
  float2 bm = *(const float2*)(ml + ((size_t)32768 + qg) * 2);
  float m = fmaxf(a.x, bm.x);
  float w0 = __expf(a.x - m), w1 = __expf(bm.x - m);
  float inv = 1.f / (a.y * w0 + bm.y * w1);
  w0 *= inv; w1 *= inv;
  const float* p0 = Opart + (size_t)qg * CH + coff;
  const float* p1 = p0 + (size_t)32768 * CH;
  floatx4 x0 = *(const floatx4*)p0, x1 = *(const floatx4*)(p0 + 4);
  floatx4 y0 = *(const floatx4*)p1, y1 = *(const floatx4*)(p1 + 4);
  alignas(16) unsigned short o[8];
#pragma unroll
  for (int i = 0; i < 4; ++i) {
    o[i]     = f2bf(x0[i] * w0 + y0[i] * w1);
    o[4 + i] = f2bf(x1[i] * w0 + y1[i] * w1);
  }
  *(intx4*)(aT + (size_t)qg * CH + coff) = *(const intx4*)o;
}

// ---------------- output projection + bias + residual ----------------
__global__ __launch_bounds__(256, 2) void out_gemm(
    const unsigned short* __restrict__ wob, const unsigned short* __restrict__ aT,
    const float* __restrict__ bo, const float* __restrict__ x, float* __restrict__ outp) {
  int nt = blockIdx.x, ot = blockIdx.y, b = blockIdx.z;
  const unsigned short* A = aT + (size_t)b * NPIX * CH;
  int o0 = ot * 128, n0 = nt * 128;

  __shared__ unsigned short As[128 * 64];
  __shared__ unsigned short Bs[128 * 64];

  int tid = threadIdx.x;
  int wave = tid >> 6, lane = tid & 63, quad = lane >> 4, l16 = lane & 15;
  int wm = (wave >> 1) * 64, wn = (wave & 1) * 64;

  floatx4 acc[4][4];
#pragma unroll
  for (int i = 0; i < 4; ++i)
#pragma unroll
    for (int j = 0; j < 4; ++j) acc[i][j] = (floatx4){0.f, 0.f, 0.f, 0.f};

  for (int k0 = 0; k0 < 256; k0 += 64) {
    __syncthreads();
#pragma unroll
    for (int c2 = 0; c2 < 4; ++c2) {
      int row = wave * 32 + c2 * 8 + (lane >> 3);
      int sc = (lane & 7) ^ (row & 7);
      gload16(wob + (size_t)(o0 + row) * CH + k0 + sc * 8, &As[(wave * 32 + c2 * 8) * 64]);
      gload16(A + (size_t)(n0 + row) * CH + k0 + sc * 8, &Bs[(wave * 32 + c2 * 8) * 64]);
    }
    __syncthreads();
#pragma unroll
    for (int s = 0; s < 2; ++s) {
      short8 af[4], bf[4];
#pragma unroll
      for (int i = 0; i < 4; ++i) {
        int m = wm + i * 16 + l16;
        af[i] = *(const short8*)(As + m * 64 + (((s * 4 + quad) ^ (m & 7)) * 8));
        int n = wn + i * 16 + l16;
        bf[i] = *(const short8*)(Bs + n * 64 + (((s * 4 + quad) ^ (n & 7)) * 8));
      }
#pragma unroll
      for (int i = 0; i < 4; ++i)
#pragma unroll
        for (int j = 0; j < 4; ++j)
          acc[i][j] = __builtin_amdgcn_mfma_f32_16x16x32_bf16(af[i], bf[j], acc[i][j], 0, 0, 0);
    }
  }

#pragma unroll
  for (int i = 0; i < 4; ++i)
#pragma unroll
    for (int r = 0; r < 4; ++r) {
      int o = o0 + wm + i * 16 + quad * 4 + r;
      float bb = bo[o];
#pragma unroll
      for (int j = 0; j < 4; ++j) {
        int n = n0 + wn + j * 16 + l16;
        size_t idx = ((size_t)b * CH + o) * NPIX + n;
        outp[idx] = x[idx] + bb + acc[i][j][r];
      }
    }
}

extern "C" void kernel_launch(void* const* d_in, const int* in_sizes, int n_in,
                              void* d_out, int out_size, void* d_ws, size_t ws_size,
                              hipStream_t stream) {
  const float* x   = (const float*)d_in[0];
  const float* gsc = (const float*)d_in[1];
  const float* gbi = (const float*)d_in[2];
  const float* wq  = (const float*)d_in[3];
  const float* bq  = (const float*)d_in[4];
  const float* wk  = (const float*)d_in[5];
  const float* bk  = (const float*)d_in[6];
  const float* wv  = (const float*)d_in[7];
  const float* bv  = (const float*)d_in[8];
  const float* wo  = (const float*)d_in[9];
  const float* bo  = (const float*)d_in[10];
  float* out = (float*)d_out;

  char* ws = (char*)d_ws;
  unsigned short* xnT  = (unsigned short*)(ws);              // 16 MB (dead after qkv)
  float*          ml   = (float*)(ws);                       // 512 KB, reuses xnT region
  unsigned short* qT   = (unsigned short*)(ws + 16777216);   // 16 MB (dead after attn)
  unsigned short* aT   = qT;                                 // reuse
  unsigned short* kT   = (unsigned short*)(ws + 33554432);   // 16 MB
  unsigned short* vC   = (unsigned short*)(ws + 50331648);   // 16 MB
  unsigned short* wqkv = (unsigned short*)(ws + 67108864);   // 384 KB
  unsigned short* wob  = (unsigned short*)(ws + 67502080);   // 128 KB
  float*          Opart= (float*)(ws + 67633152);            // 64 MB

  conv_weights_kernel<<<256, 256, 0, stream>>>(wq, wk, wv, wo, wqkv, wob);
  gn_kernel<<<256, 256, 0, stream>>>(x, gsc, gbi, xnT);
  dim3 g1(32, 2, 24);
  qkv_gemm<<<g1, 256, 0, stream>>>(wqkv, xnT, bq, bk, bv, qT, kT, vC);
  dim3 g2(32, 2, 8);
  attn_kernel<<<g2, 256, 0, stream>>>(qT, kT, vC, Opart, ml);
  combine_kernel<<<4096, 256, 0, stream>>>(Opart, ml, aT);
  dim3 g3(32, 2, 8);
  out_gemm<<<g3, 256, 0, stream>>>(wob, aT, bo, x, out);
}

// Round 3
// 431.924 us; speedup vs baseline: 1.4150x; 1.4150x over previous
//
#include <hip/hip_runtime.h>

typedef __attribute__((ext_vector_type(8))) short short8;
typedef __attribute__((ext_vector_type(4))) float floatx4;
typedef __attribute__((ext_vector_type(4))) int intx4;

#define NPIX 4096
#define CH 256

static __device__ __forceinline__ unsigned short f2bf(float f) {
  union { float f; unsigned int u; } v; v.f = f;
  unsigned int u = v.u;
  return (unsigned short)((u + 0x7FFFu + ((u >> 16) & 1u)) >> 16);
}

typedef __attribute__((address_space(3))) unsigned int lds_uint;
typedef const __attribute__((address_space(1))) unsigned int glob_uint;
static __device__ __forceinline__ void gload16(const void* g, void* l) {
  __builtin_amdgcn_global_load_lds((glob_uint*)g, (lds_uint*)l, 16, 0, 0);
}

// ---------------- weights fp32 -> bf16 ----------------
__global__ void conv_weights_kernel(const float* __restrict__ wq, const float* __restrict__ wk,
                                    const float* __restrict__ wv, const float* __restrict__ wo,
                                    unsigned short* __restrict__ wqkv, unsigned short* __restrict__ wob) {
  int i = blockIdx.x * 256 + threadIdx.x;   // 0..65535
  wqkv[i]          = f2bf(wq[i]);
  wqkv[65536 + i]  = f2bf(wk[i]);
  wqkv[131072 + i] = f2bf(wv[i]);
  wob[i]           = f2bf(wo[i]);
}

// ---------------- GroupNorm -> xnT bf16 [b][n][c] ----------------
__global__ __launch_bounds__(256) void gn_kernel(const float* __restrict__ x,
                                                 const float* __restrict__ gsc,
                                                 const float* __restrict__ gbi,
                                                 unsigned short* __restrict__ xnT) {
  int blk = blockIdx.x; int b = blk >> 5; int g = blk & 31;
  int c0 = g * 8;
  const float* xb = x + ((size_t)b * CH + c0) * NPIX;
  int tid = threadIdx.x;
  float s = 0.f, ss = 0.f;
#pragma unroll
  for (int ci = 0; ci < 8; ++ci) {
    const floatx4* p = (const floatx4*)(xb + (size_t)ci * NPIX);
    for (int n4 = tid; n4 < 1024; n4 += 256) {
      floatx4 v = p[n4];
      s += v[0] + v[1] + v[2] + v[3];
      ss += v[0]*v[0] + v[1]*v[1] + v[2]*v[2] + v[3]*v[3];
    }
  }
#pragma unroll
  for (int o = 32; o > 0; o >>= 1) { s += __shfl_down(s, o); ss += __shfl_down(ss, o); }
  __shared__ float red[10];
  int wid = tid >> 6;
  if ((tid & 63) == 0) { red[wid] = s; red[4 + wid] = ss; }
  __syncthreads();
  if (tid == 0) {
    float S = red[0] + red[1] + red[2] + red[3];
    float SS = red[4] + red[5] + red[6] + red[7];
    float mean = S * (1.f / 32768.f);
    float var = SS * (1.f / 32768.f) - mean * mean;
    red[8] = mean; red[9] = rsqrtf(var + 1e-5f);
  }
  __syncthreads();
  float mean = red[8], rstd = red[9];
  float sc[8], bi[8];
#pragma unroll
  for (int ci = 0; ci < 8; ++ci) {
    float scale = gsc[c0 + ci] * rstd;
    sc[ci] = scale;
    bi[ci] = gbi[c0 + ci] - mean * scale;
  }
  for (int n4 = tid; n4 < 1024; n4 += 256) {
    floatx4 v[8];
#pragma unroll
    for (int ci = 0; ci < 8; ++ci) v[ci] = ((const floatx4*)(xb + (size_t)ci * NPIX))[n4];
#pragma unroll
    for (int j = 0; j < 4; ++j) {
      alignas(16) unsigned short tmp[8];
#pragma unroll
      for (int ci = 0; ci < 8; ++ci) tmp[ci] = f2bf(v[ci][j] * sc[ci] + bi[ci]);
      *(intx4*)(xnT + ((size_t)(b * NPIX + n4 * 4 + j)) * CH + c0) = *(const intx4*)tmp;
    }
  }
}

// ---------------- QKV GEMM: D[o,n] = sum_c W[o,c]*xnT[n,c] + bias ----------------
// q (pre-scaled by 1/16), k written [n][o] bf16 ; v written [o][n] bf16
__global__ __launch_bounds__(256, 2) void qkv_gemm(
    const unsigned short* __restrict__ wqkv, const unsigned short* __restrict__ xnT,
    const float* __restrict__ bq, const float* __restrict__ bk, const float* __restrict__ bv,
    unsigned short* __restrict__ qT, unsigned short* __restrict__ kT, unsigned short* __restrict__ vC) {
  int nt = blockIdx.x, ot = blockIdx.y, bz = blockIdx.z;
  int which = bz % 3, b = bz / 3;
  const unsigned short* W = wqkv + which * 65536;
  const float* bias = which == 0 ? bq : (which == 1 ? bk : bv);
  const unsigned short* X = xnT + (size_t)b * NPIX * CH;
  int o0 = ot * 128, n0 = nt * 128;

  __shared__ unsigned short As[128 * 64];
  __shared__ unsigned short Bs[128 * 64];

  int tid = threadIdx.x;
  int wave = tid >> 6, lane = tid & 63, quad = lane >> 4, l16 = lane & 15;
  int wm = (wave >> 1) * 64, wn = (wave & 1) * 64;

  floatx4 acc[4][4];
#pragma unroll
  for (int i = 0; i < 4; ++i)
#pragma unroll
    for (int j = 0; j < 4; ++j) acc[i][j] = (floatx4){0.f, 0.f, 0.f, 0.f};

  for (int k0 = 0; k0 < 256; k0 += 64) {
    __syncthreads();
#pragma unroll
    for (int c2 = 0; c2 < 4; ++c2) {
      int row = wave * 32 + c2 * 8 + (lane >> 3);
      int sc = (lane & 7) ^ (row & 7);
      gload16(W + (size_t)(o0 + row) * CH + k0 + sc * 8, &As[(wave * 32 + c2 * 8) * 64]);
      gload16(X + (size_t)(n0 + row) * CH + k0 + sc * 8, &Bs[(wave * 32 + c2 * 8) * 64]);
    }
    __syncthreads();
#pragma unroll
    for (int s = 0; s < 2; ++s) {
      short8 af[4], bf[4];
#pragma unroll
      for (int i = 0; i < 4; ++i) {
        int m = wm + i * 16 + l16;
        af[i] = *(const short8*)(As + m * 64 + (((s * 4 + quad) ^ (m & 7)) * 8));
        int n = wn + i * 16 + l16;
        bf[i] = *(const short8*)(Bs + n * 64 + (((s * 4 + quad) ^ (n & 7)) * 8));
      }
#pragma unroll
      for (int i = 0; i < 4; ++i)
#pragma unroll
        for (int j = 0; j < 4; ++j)
          acc[i][j] = __builtin_amdgcn_mfma_f32_16x16x32_bf16(af[i], bf[j], acc[i][j], 0, 0, 0);
    }
  }

  if (which < 2) {
    float qs = (which == 0) ? 0.0625f : 1.0f;   // fold 1/sqrt(256) into Q
    unsigned short* outp = (which == 0 ? qT : kT) + (size_t)b * NPIX * CH;
#pragma unroll
    for (int i = 0; i < 4; ++i) {
      int obase = o0 + wm + i * 16 + quad * 4;
      float bias4[4];
#pragma unroll
      for (int r = 0; r < 4; ++r) bias4[r] = bias[obase + r];
#pragma unroll
      for (int j = 0; j < 4; ++j) {
        int n = n0 + wn + j * 16 + l16;
        unsigned long long pk = 0;
#pragma unroll
        for (int r = 0; r < 4; ++r)
          pk |= (unsigned long long)f2bf((acc[i][j][r] + bias4[r]) * qs) << (16 * r);
        *(unsigned long long*)(outp + (size_t)n * CH + obase) = pk;
      }
    }
  } else {
    unsigned short* outp = vC + (size_t)b * CH * NPIX;
#pragma unroll
    for (int i = 0; i < 4; ++i)
#pragma unroll
      for (int r = 0; r < 4; ++r) {
        int o = o0 + wm + i * 16 + quad * 4 + r;
        float bb = bias[o];
#pragma unroll
        for (int j = 0; j < 4; ++j) {
          int n = n0 + wn + j * 16 + l16;
          outp[(size_t)o * NPIX + n] = f2bf(acc[i][j][r] + bb);
        }
      }
  }
}

// ---------------- flash attention (S^T form, 2-way K-split, XCD-pinned b) ----------------
// grid 1024 x 128 threads (2 waves x 32 q = 64 q/block). KTILE=32, 64 iters.
// b = blockIdx.x & 7 so all blocks on an XCD share one b's K/V (L2-resident 4MB).
__global__ __launch_bounds__(128, 2) void attn_kernel(
    const unsigned short* __restrict__ qT, const unsigned short* __restrict__ kT,
    const unsigned short* __restrict__ vC, float* __restrict__ Opart, float* __restrict__ ml) {
  __shared__ unsigned short Klds[32 * 256];   // 16KB [k-row][c] chunk-swizzled
  __shared__ unsigned short Vlds[256 * 32];   // 16KB [c][m] chunk-swizzled
  __shared__ unsigned short Plds[2][32 * 32]; // 2KB per wave

  const int tid = threadIdx.x;
  const int wave = tid >> 6, lane = tid & 63;
  const int quad = lane >> 4, l16 = lane & 15;
  const int bid = blockIdx.x;
  const int b = bid & 7, rest = bid >> 3;
  const int split = rest & 1, nt = rest >> 1;   // nt 0..63
  const int q0 = nt * 64 + wave * 32;

  const unsigned short* Kb = kT + (size_t)b * NPIX * CH;
  const unsigned short* Vb = vC + (size_t)b * CH * NPIX;

  // Q fragments: B[k=c][n=q], two 16-q sub-tiles per wave
  short8 qf[2][8];
#pragma unroll
  for (int qb = 0; qb < 2; ++qb) {
    const unsigned short* qp = qT + ((size_t)(b * NPIX + q0 + qb * 16 + l16)) * CH + quad * 8;
#pragma unroll
    for (int s = 0; s < 8; ++s) qf[qb][s] = *(const short8*)(qp + s * 32);
  }

  floatx4 oacc[16][2];   // O^T: [c-tile][qb] -> D[c][q]
#pragma unroll
  for (int cb = 0; cb < 16; ++cb) { oacc[cb][0] = (floatx4){0,0,0,0}; oacc[cb][1] = (floatx4){0,0,0,0}; }
  float m_i[2] = {-1e30f, -1e30f}, l_i[2] = {0.f, 0.f};

  unsigned short* Pw = Plds[wave];

  for (int kt = 0; kt < 64; ++kt) {
    const int m0 = split * 2048 + kt * 32;
    __syncthreads();
    if (wave == 0) {
#pragma unroll
      for (int c2 = 0; c2 < 16; ++c2) {
        int krow = c2 * 2 + (lane >> 5);
        gload16(Kb + (size_t)(m0 + krow) * CH + (((lane & 31) ^ (krow & 7)) * 8),
                &Klds[c2 * 2 * CH]);
      }
    } else {
#pragma unroll
      for (int c2 = 0; c2 < 16; ++c2) {
        int vrow = c2 * 16 + (lane >> 2);
        gload16(Vb + (size_t)vrow * NPIX + m0 + (((lane & 3) ^ (vrow & 3)) * 8),
                &Vlds[c2 * 16 * 32]);
      }
    }
    __syncthreads();

    // S^T = K Q^T : D[k][q]; kf shared across both q sub-tiles
    floatx4 sacc[2][2];   // [qb][kb]
#pragma unroll
    for (int kb = 0; kb < 2; ++kb) { sacc[0][kb] = (floatx4){0,0,0,0}; sacc[1][kb] = (floatx4){0,0,0,0}; }
#pragma unroll
    for (int s = 0; s < 8; ++s) {
#pragma unroll
      for (int kb = 0; kb < 2; ++kb) {
        int m = kb * 16 + l16;
        short8 kf = *(const short8*)&Klds[m * CH + (((s * 4 + quad) ^ (m & 7)) * 8)];
        sacc[0][kb] = __builtin_amdgcn_mfma_f32_16x16x32_bf16(kf, qf[0][s], sacc[0][kb], 0, 0, 0);
        sacc[1][kb] = __builtin_amdgcn_mfma_f32_16x16x32_bf16(kf, qf[1][s], sacc[1][kb], 0, 0, 0);
      }
    }

    // online softmax, per-lane q (scale pre-folded into Q)
    float alpha[2];
#pragma unroll
    for (int qb = 0; qb < 2; ++qb) {
      float mx = sacc[qb][0][0];
#pragma unroll
      for (int kb = 0; kb < 2; ++kb)
#pragma unroll
        for (int r = 0; r < 4; ++r) mx = fmaxf(mx, sacc[qb][kb][r]);
      mx = fmaxf(mx, __shfl_xor(mx, 16));
      mx = fmaxf(mx, __shfl_xor(mx, 32));
      float mn = fmaxf(m_i[qb], mx);
      alpha[qb] = __expf(m_i[qb] - mn); m_i[qb] = mn;
      float sum = 0.f;
#pragma unroll
      for (int kb = 0; kb < 2; ++kb)
#pragma unroll
        for (int r = 0; r < 4; ++r) { float p = __expf(sacc[qb][kb][r] - mn); sacc[qb][kb][r] = p; sum += p; }
      sum += __shfl_xor(sum, 16);
      sum += __shfl_xor(sum, 32);
      l_i[qb] = l_i[qb] * alpha[qb] + sum;
    }

    // P -> per-wave LDS (packed b64), rows q(32) x cols k(32)
#pragma unroll
    for (int qb = 0; qb < 2; ++qb)
#pragma unroll
      for (int kb = 0; kb < 2; ++kb) {
        int row = qb * 16 + l16;
        int phys = (kb * 2 + (quad >> 1)) ^ (l16 & 3);
        uint2 w;
        w.x = (unsigned int)f2bf(sacc[qb][kb][0]) | ((unsigned int)f2bf(sacc[qb][kb][1]) << 16);
        w.y = (unsigned int)f2bf(sacc[qb][kb][2]) | ((unsigned int)f2bf(sacc[qb][kb][3]) << 16);
        *(uint2*)&Pw[row * 32 + phys * 8 + (quad & 1) * 4] = w;
      }

    // rescale O while P writes drain
#pragma unroll
    for (int cb = 0; cb < 16; ++cb)
#pragma unroll
      for (int r = 0; r < 4; ++r) { oacc[cb][0][r] *= alpha[0]; oacc[cb][1][r] *= alpha[1]; }

    asm volatile("s_waitcnt lgkmcnt(0)" ::: "memory");
    short8 pf0 = *(const short8*)&Pw[l16 * 32 + ((quad ^ (l16 & 3)) * 8)];
    short8 pf1 = *(const short8*)&Pw[(16 + l16) * 32 + ((quad ^ (l16 & 3)) * 8)];

    // O^T += V P^T : vf shared across both q sub-tiles
#pragma unroll
    for (int cb = 0; cb < 16; ++cb) {
      int c = cb * 16 + l16;
      short8 vf = *(const short8*)&Vlds[c * 32 + ((quad ^ (c & 3)) * 8)];
      oacc[cb][0] = __builtin_amdgcn_mfma_f32_16x16x32_bf16(vf, pf0, oacc[cb][0], 0, 0, 0);
      oacc[cb][1] = __builtin_amdgcn_mfma_f32_16x16x32_bf16(vf, pf1, oacc[cb][1], 0, 0, 0);
    }
  }

  // epilogue: partial O (fp32, unnormalized) + (m,l)
#pragma unroll
  for (int qb = 0; qb < 2; ++qb) {
    int q = q0 + qb * 16 + l16;
    float* op = Opart + ((size_t)(split * 8 + b) * NPIX + q) * CH + quad * 4;
#pragma unroll
    for (int cb = 0; cb < 16; ++cb) *(floatx4*)(op + cb * 16) = oacc[cb][qb];
    if (quad == 0) {
      float* mp = ml + ((size_t)(split * 8 + b) * NPIX + q) * 2;
      mp[0] = m_i[qb]; mp[1] = l_i[qb];
    }
  }
}

// ---------------- combine the 2 K-split partials -> aT bf16 [n][c] ----------------
__global__ __launch_bounds__(256) void combine_kernel(const float* __restrict__ Opart,
                                                      const float* __restrict__ ml,
                                                      unsigned short* __restrict__ aT) {
  int t = blockIdx.x * 256 + threadIdx.x;   // 1M threads, 8 c each
  int qg = t >> 5;
  int coff = (t & 31) << 3;
  float2 a = *(const float2*)(ml + (size_t)qg * 2);
  float2 bm = *(const float2*)(ml + ((size_t)32768 + qg) * 2);
  float m = fmaxf(a.x, bm.x);
  float w0 = __expf(a.x - m), w1 = __expf(bm.x - m);
  float inv = 1.f / (a.y * w0 + bm.y * w1);
  w0 *= inv; w1 *= inv;
  const float* p0 = Opart + (size_t)qg * CH + coff;
  const float* p1 = p0 + (size_t)32768 * CH;
  floatx4 x0 = *(const floatx4*)p0, x1 = *(const floatx4*)(p0 + 4);
  floatx4 y0 = *(const floatx4*)p1, y1 = *(const floatx4*)(p1 + 4);
  alignas(16) unsigned short o[8];
#pragma unroll
  for (int i = 0; i < 4; ++i) {
    o[i]     = f2bf(x0[i] * w0 + y0[i] * w1);
    o[4 + i] = f2bf(x1[i] * w0 + y1[i] * w1);
  }
  *(intx4*)(aT + (size_t)qg * CH + coff) = *(const intx4*)o;
}

// ---------------- output projection + bias + residual ----------------
__global__ __launch_bounds__(256, 2) void out_gemm(
    const unsigned short* __restrict__ wob, const unsigned short* __restrict__ aT,
    const float* __restrict__ bo, const float* __restrict__ x, float* __restrict__ outp) {
  int nt = blockIdx.x, ot = blockIdx.y, b = blockIdx.z;
  const unsigned short* A = aT + (size_t)b * NPIX * CH;
  int o0 = ot * 128, n0 = nt * 128;

  __shared__ unsigned short As[128 * 64];
  __shared__ unsigned short Bs[128 * 64];

  int tid = threadIdx.x;
  int wave = tid >> 6, lane = tid & 63, quad = lane >> 4, l16 = lane & 15;
  int wm = (wave >> 1) * 64, wn = (wave & 1) * 64;

  floatx4 acc[4][4];
#pragma unroll
  for (int i = 0; i < 4; ++i)
#pragma unroll
    for (int j = 0; j < 4; ++j) acc[i][j] = (floatx4){0.f, 0.f, 0.f, 0.f};

  for (int k0 = 0; k0 < 256; k0 += 64) {
    __syncthreads();
#pragma unroll
    for (int c2 = 0; c2 < 4; ++c2) {
      int row = wave * 32 + c2 * 8 + (lane >> 3);
      int sc = (lane & 7) ^ (row & 7);
      gload16(wob + (size_t)(o0 + row) * CH + k0 + sc * 8, &As[(wave * 32 + c2 * 8) * 64]);
      gload16(A + (size_t)(n0 + row) * CH + k0 + sc * 8, &Bs[(wave * 32 + c2 * 8) * 64]);
    }
    __syncthreads();
#pragma unroll
    for (int s = 0; s < 2; ++s) {
      short8 af[4], bf[4];
#pragma unroll
      for (int i = 0; i < 4; ++i) {
        int m = wm + i * 16 + l16;
        af[i] = *(const short8*)(As + m * 64 + (((s * 4 + quad) ^ (m & 7)) * 8));
        int n = wn + i * 16 + l16;
        bf[i] = *(const short8*)(Bs + n * 64 + (((s * 4 + quad) ^ (n & 7)) * 8));
      }
#pragma unroll
      for (int i = 0; i < 4; ++i)
#pragma unroll
        for (int j = 0; j < 4; ++j)
          acc[i][j] = __builtin_amdgcn_mfma_f32_16x16x32_bf16(af[i], bf[j], acc[i][j], 0, 0, 0);
    }
  }

#pragma unroll
  for (int i = 0; i < 4; ++i)
#pragma unroll
    for (int r = 0; r < 4; ++r) {
      int o = o0 + wm + i * 16 + quad * 4 + r;
      float bb = bo[o];
#pragma unroll
      for (int j = 0; j < 4; ++j) {
        int n = n0 + wn + j * 16 + l16;
        size_t idx = ((size_t)b * CH + o) * NPIX + n;
        outp[idx] = x[idx] + bb + acc[i][j][r];
      }
    }
}

extern "C" void kernel_launch(void* const* d_in, const int* in_sizes, int n_in,
                              void* d_out, int out_size, void* d_ws, size_t ws_size,
                              hipStream_t stream) {
  const float* x   = (const float*)d_in[0];
  const float* gsc = (const float*)d_in[1];
  const float* gbi = (const float*)d_in[2];
  const float* wq  = (const float*)d_in[3];
  const float* bq  = (const float*)d_in[4];
  const float* wk  = (const float*)d_in[5];
  const float* bk  = (const float*)d_in[6];
  const float* wv  = (const float*)d_in[7];
  const float* bv  = (const float*)d_in[8];
  const float* wo  = (const float*)d_in[9];
  const float* bo  = (const float*)d_in[10];
  float* out = (float*)d_out;

  char* ws = (char*)d_ws;
  unsigned short* xnT  = (unsigned short*)(ws);              // 16 MB (dead after qkv)
  float*          ml   = (float*)(ws);                       // 512 KB, reuses xnT region
  unsigned short* qT   = (unsigned short*)(ws + 16777216);   // 16 MB (dead after attn)
  unsigned short* aT   = qT;                                 // reuse
  unsigned short* kT   = (unsigned short*)(ws + 33554432);   // 16 MB
  unsigned short* vC   = (unsigned short*)(ws + 50331648);   // 16 MB
  unsigned short* wqkv = (unsigned short*)(ws + 67108864);   // 384 KB
  unsigned short* wob  = (unsigned short*)(ws + 67502080);   // 128 KB
  float*          Opart= (float*)(ws + 67633152);            // 64 MB

  conv_weights_kernel<<<256, 256, 0, stream>>>(wq, wk, wv, wo, wqkv, wob);
  gn_kernel<<<256, 256, 0, stream>>>(x, gsc, gbi, xnT);
  dim3 g1(32, 2, 24);
  qkv_gemm<<<g1, 256, 0, stream>>>(wqkv, xnT, bq, bk, bv, qT, kT, vC);
  attn_kernel<<<1024, 128, 0, stream>>>(qT, kT, vC, Opart, ml);
  combine_kernel<<<4096, 256, 0, stream>>>(Opart, ml, aT);
  dim3 g3(32, 2, 8);
  out_gemm<<<g3, 256, 0, stream>>>(wob, aT, bo, x, out);
}